// Round 3
// baseline (729.070 us; speedup 1.0000x reference)
//
#include <hip/hip_runtime.h>

#define DEV __device__ __forceinline__

typedef float          f32x4  __attribute__((ext_vector_type(4)));
typedef __bf16         bf16x8 __attribute__((ext_vector_type(8)));
typedef unsigned short u16x8  __attribute__((ext_vector_type(8)));
typedef unsigned short u16x4  __attribute__((ext_vector_type(4)));

static constexpr int  Bq   = 256;   // batch
static constexpr int  Qs   = 128;   // seq len
static constexpr int  Dm   = 256;   // model dim
static constexpr int  Ff   = 512;   // ffn dim
static constexpr int  ROWS = Bq * Qs;               // 32768
static constexpr long QK_LSTR = (long)ROWS * 512;   // q||k history per layer

DEV unsigned short f2b(float f) {
    unsigned int u; __builtin_memcpy(&u, &f, 4);
    u += 0x7fffu + ((u >> 16) & 1u);   // RNE
    return (unsigned short)(u >> 16);
}
DEV f32x4 mfma_bf16(u16x8 a, u16x8 b, f32x4 c) {
    return __builtin_amdgcn_mfma_f32_16x16x32_bf16(
        __builtin_bit_cast(bf16x8, a), __builtin_bit_cast(bf16x8, b), c, 0, 0, 0);
}

// ---------------- embed: z = x @ W_P + b_P + W_pos (all f32 in) ----------------
__global__ void k_embed(const float* __restrict__ x,
                        const float* __restrict__ WP,
                        const float* __restrict__ bP,
                        const float* __restrict__ Wpos,
                        float* __restrict__ zf, unsigned short* __restrict__ zb) {
    int row = blockIdx.x;            // b*Q + q
    int d   = threadIdx.x;           // 0..255
    int q   = row & (Qs - 1);
    const float* xr = x + row * 16;
    float acc = bP[d] + Wpos[q * Dm + d];
#pragma unroll
    for (int p = 0; p < 16; p++) acc += xr[p] * WP[p * Dm + d];
    zf[(long)row * Dm + d] = acc;
    zb[(long)row * Dm + d] = f2b(acc);
}

// ---------------- weight transpose+cast: out_bf16[N x K] = in_f32[K x N]^T, L slices ----------------
__global__ void k_transpose(const float* __restrict__ in,
                            unsigned short* __restrict__ out,
                            int K, int N, long outSlice, long outOff) {
    long idx = (long)blockIdx.x * blockDim.x + threadIdx.x;
    int per = K * N;
    int l = (int)(idx / per);
    int r = (int)(idx - (long)l * per);
    int n = r / K;
    int k = r - n * K;
    out[(long)l * outSlice + outOff + (long)n * K + k] = f2b(in[(long)l * per + (long)k * N + n]);
}

// ---------------- pack bq|bk|bv into (3,768) f32 ----------------
__global__ void k_biasqkv(const float* __restrict__ bq,
                          const float* __restrict__ bk,
                          const float* __restrict__ bv,
                          float* __restrict__ o) {
    int idx = blockIdx.x * 256 + threadIdx.x;   // < 2304
    int l = idx / 768, j = idx % 768;
    float v = (j < 256) ? bq[l * 256 + j]
            : (j < 512) ? bk[l * 256 + j - 256]
                        : bv[l * 256 + j - 512];
    o[idx] = v;
}

// ---------------- GEMM: C = act(A[MxK] @ W[KxN] + bias), W given as WT[NxK] bf16 ----------------
// 128x128 block tile, 4 waves in 2x2 quadrants of 64x64, 16x16x32 bf16 MFMA, BK=32.
// MODE: 0 = bf16 out (stride N), 1 = f32 out (stride N), 2 = qkv split:
//       col<512 -> outB (stride 512), col>=512 -> aux (stride 256)
template <int GELU, int MODE>
__global__ __launch_bounds__(256) void k_gemm(const unsigned short* __restrict__ A,
                                              const unsigned short* __restrict__ WT,
                                              const float* __restrict__ bias,
                                              unsigned short* __restrict__ outB,
                                              float* __restrict__ outF,
                                              unsigned short* __restrict__ aux,
                                              int M, int N, int K) {
    __shared__ unsigned short As[128 * 32];
    __shared__ unsigned short Bs[128 * 32];
    const int tid  = threadIdx.x;
    const int wave = tid >> 6, lane = tid & 63, quad = lane >> 4, l16 = lane & 15;
    const int mq = wave >> 1, nq = wave & 1;
    const int m_blk = blockIdx.x * 128, n_blk = blockIdx.y * 128;

    f32x4 acc[4][4] = {};

    for (int k0 = 0; k0 < K; k0 += 32) {
#pragma unroll
        for (int i = 0; i < 2; i++) {
            int c = tid + i * 256;           // 16B chunk id, 512 chunks per tile
            int row = c >> 2, col = (c & 3) * 8;
            *(u16x8*)&As[c * 8] = *(const u16x8*)(A  + (long)(m_blk + row) * K + k0 + col);
            *(u16x8*)&Bs[c * 8] = *(const u16x8*)(WT + (long)(n_blk + row) * K + k0 + col);
        }
        __syncthreads();
        u16x8 af[4], bf[4];
#pragma unroll
        for (int i = 0; i < 4; i++)
            af[i] = *(const u16x8*)&As[(64 * mq + 16 * i + l16) * 32 + quad * 8];
#pragma unroll
        for (int j = 0; j < 4; j++)
            bf[j] = *(const u16x8*)&Bs[(64 * nq + 16 * j + l16) * 32 + quad * 8];
#pragma unroll
        for (int i = 0; i < 4; i++)
#pragma unroll
            for (int j = 0; j < 4; j++)
                acc[i][j] = mfma_bf16(af[i], bf[j], acc[i][j]);
        __syncthreads();
    }

#pragma unroll
    for (int i = 0; i < 4; i++) {
        int row = m_blk + 64 * mq + 16 * i + quad * 4;   // C row = quad*4 + reg
#pragma unroll
        for (int j = 0; j < 4; j++) {
            int col = n_blk + 64 * nq + 16 * j + l16;    // C col = lane&15
            float bb = bias[col];
#pragma unroll
            for (int r = 0; r < 4; r++) {
                float v = acc[i][j][r] + bb;
                if (GELU) v = 0.5f * v * (1.0f + erff(v * 0.70710678118f));
                if (MODE == 0) outB[(long)(row + r) * N + col] = f2b(v);
                if (MODE == 1) outF[(long)(row + r) * N + col] = v;
                if (MODE == 2) {
                    if (col < 512) outB[(long)(row + r) * 512 + col] = f2b(v);
                    else           aux [(long)(row + r) * 256 + (col - 512)] = f2b(v);
                }
            }
        }
    }
}

// ---------------- fused attention for layer L (score-carry recompute) ----------------
// grid = B*H blocks; block = 256 thr (4 waves, 32 S-rows each).
// S = scale * sum_{i<=L} q_i k_i^T + (L+1)*bias ; P = softmax(S) ; O = P @ v_L
__global__ __launch_bounds__(256) void k_attn(const unsigned short* __restrict__ qk,
                                              const unsigned short* __restrict__ vbuf,
                                              const float* __restrict__ ab,
                                              unsigned short* __restrict__ o_out, int L) {
    __shared__ unsigned short qs[128 * 24];   // ld 24
    __shared__ unsigned short ks[128 * 24];
    __shared__ unsigned short vt[16 * 136];   // v^T [dk][key]
    __shared__ unsigned short Ps[128 * 136];  // probs, ld 136
    const int tid  = threadIdx.x;
    const int wave = tid >> 6, lane = tid & 63, quad = lane >> 4, l16 = lane & 15;
    const int b = blockIdx.x >> 4, h = blockIdx.x & 15;
    const long rowqk = (long)(b * Qs) * 512 + h * 16;
    const int qrow = tid >> 1, half = tid & 1;

    f32x4 accS[2][8] = {};
    u16x8 zero = {};

    for (int li = 0; li <= L; li++) {
        const unsigned short* base = qk + li * QK_LSTR;
        u16x8 qv = *(const u16x8*)(base + rowqk + (long)qrow * 512 + half * 8);
        u16x8 kv = *(const u16x8*)(base + rowqk + (long)qrow * 512 + 256 + half * 8);
        *(u16x8*)&qs[qrow * 24 + half * 8] = qv;
        *(u16x8*)&ks[qrow * 24 + half * 8] = kv;
        __syncthreads();
        u16x8 af[2], bf[8];
#pragma unroll
        for (int i = 0; i < 2; i++) {
            int m = 32 * wave + 16 * i + l16;
            af[i] = (quad < 2) ? *(const u16x8*)&qs[m * 24 + quad * 8] : zero;  // K=16: quads 2,3 zero
        }
#pragma unroll
        for (int j = 0; j < 8; j++) {
            int n = 16 * j + l16;
            bf[j] = (quad < 2) ? *(const u16x8*)&ks[n * 24 + quad * 8] : zero;
        }
#pragma unroll
        for (int i = 0; i < 2; i++)
#pragma unroll
            for (int j = 0; j < 8; j++)
                accS[i][j] = mfma_bf16(af[i], bf[j], accS[i][j]);
        __syncthreads();
    }

    // stage v^T (current layer)
    {
        u16x8 vv = *(const u16x8*)(vbuf + (long)(b * Qs + qrow) * 256 + h * 16 + half * 8);
#pragma unroll
        for (int jj = 0; jj < 8; jj++) vt[(half * 8 + jj) * 136 + qrow] = vv[jj];
    }

    // scale + bias + row softmax -> Ps (bf16)
    const float scale = 0.25f;            // DK^-0.5, DK=16
    const float bm = (float)(L + 1);      // bias accumulates once per layer in the carry
#pragma unroll
    for (int i = 0; i < 2; i++) {
#pragma unroll
        for (int r = 0; r < 4; r++) {
            int m = 32 * wave + 16 * i + quad * 4 + r;
            float vals[8];
#pragma unroll
            for (int j = 0; j < 8; j++)
                vals[j] = accS[i][j][r] * scale + bm * ab[m * 128 + 16 * j + l16];
            float mx = vals[0];
#pragma unroll
            for (int j = 1; j < 8; j++) mx = fmaxf(mx, vals[j]);
            for (int mk = 1; mk < 16; mk <<= 1) mx = fmaxf(mx, __shfl_xor(mx, mk));
            float sum = 0.f;
#pragma unroll
            for (int j = 0; j < 8; j++) { vals[j] = __expf(vals[j] - mx); sum += vals[j]; }
            for (int mk = 1; mk < 16; mk <<= 1) sum += __shfl_xor(sum, mk);
            float inv = 1.0f / sum;
#pragma unroll
            for (int j = 0; j < 8; j++) Ps[m * 136 + 16 * j + l16] = f2b(vals[j] * inv);
        }
    }
    __syncthreads();

    // O = P @ v : M=128, N=16, K=128
    f32x4 accO[2] = {};
#pragma unroll
    for (int s = 0; s < 4; s++) {
        u16x8 bv = *(const u16x8*)&vt[l16 * 136 + s * 32 + quad * 8];
#pragma unroll
        for (int i = 0; i < 2; i++) {
            u16x8 ap = *(const u16x8*)&Ps[(32 * wave + 16 * i + l16) * 136 + s * 32 + quad * 8];
            accO[i] = mfma_bf16(ap, bv, accO[i]);
        }
    }
#pragma unroll
    for (int i = 0; i < 2; i++)
#pragma unroll
        for (int r = 0; r < 4; r++) {
            int m = 32 * wave + 16 * i + quad * 4 + r;
            o_out[(long)(b * Qs + m) * Dm + h * 16 + l16] = f2b(accO[i][r]);
        }
}

// ---------------- residual add + LayerNorm (wave per row), f32 params ----------------
__global__ __launch_bounds__(256) void k_addln(const float* __restrict__ zin,
                                               const float* __restrict__ add,
                                               const float* __restrict__ g,
                                               const float* __restrict__ bb,
                                               float* __restrict__ zf,
                                               unsigned short* __restrict__ zb) {
    int row  = blockIdx.x * 4 + (threadIdx.x >> 6);
    int lane = threadIdx.x & 63;
    const float4 zv = *(const float4*)(zin + (long)row * Dm + lane * 4);
    const float4 av = *(const float4*)(add + (long)row * Dm + lane * 4);
    float s[4] = {zv.x + av.x, zv.y + av.y, zv.z + av.z, zv.w + av.w};
    float sum = s[0] + s[1] + s[2] + s[3];
    for (int mk = 1; mk < 64; mk <<= 1) sum += __shfl_xor(sum, mk);
    float mean = sum * (1.0f / 256.0f);
    float d0[4], var = 0.f;
#pragma unroll
    for (int c = 0; c < 4; c++) { d0[c] = s[c] - mean; var += d0[c] * d0[c]; }
    for (int mk = 1; mk < 64; mk <<= 1) var += __shfl_xor(var, mk);
    float rstd = rsqrtf(var * (1.0f / 256.0f) + 1e-5f);
    float o[4]; u16x4 ob;
#pragma unroll
    for (int c = 0; c < 4; c++) {
        int col = lane * 4 + c;
        o[c] = d0[c] * rstd * g[col] + bb[col];
        ob[c] = f2b(o[c]);
    }
    *(float4*)(zf + (long)row * Dm + lane * 4) = make_float4(o[0], o[1], o[2], o[3]);
    *(u16x4*)(zb + (long)row * Dm + lane * 4) = ob;
}

extern "C" void kernel_launch(void* const* d_in, const int* in_sizes, int n_in,
                              void* d_out, int out_size, void* d_ws, size_t ws_size,
                              hipStream_t stream) {
    const float* x     = (const float*)d_in[0];
    const float* abias = (const float*)d_in[1];
    const float* WP    = (const float*)d_in[2];
    const float* bP    = (const float*)d_in[3];
    const float* Wpos  = (const float*)d_in[4];
    const float* Wq    = (const float*)d_in[5];
    const float* bqp   = (const float*)d_in[6];
    const float* Wk    = (const float*)d_in[7];
    const float* bkp   = (const float*)d_in[8];
    const float* Wv    = (const float*)d_in[9];
    const float* bvp   = (const float*)d_in[10];
    const float* Wo    = (const float*)d_in[11];
    const float* bo    = (const float*)d_in[12];
    const float* g1    = (const float*)d_in[13];
    const float* be1   = (const float*)d_in[14];
    const float* W1    = (const float*)d_in[15];
    const float* b1    = (const float*)d_in[16];
    const float* W2    = (const float*)d_in[17];
    const float* b2    = (const float*)d_in[18];
    const float* g2    = (const float*)d_in[19];
    const float* be2   = (const float*)d_in[20];
    (void)in_sizes; (void)n_in; (void)out_size; (void)ws_size;

    char* ws = (char*)d_ws;
    size_t off = 0;
    auto alloc = [&](size_t bytes) -> char* {
        char* p = ws + off; off += (bytes + 255) & ~(size_t)255; return p;
    };
    // total ~238 MB of workspace (fits 256 MiB)
    float*          z_f32 = (float*)alloc((size_t)ROWS * Dm * 4);               // 33.5 MB
    unsigned short* z_b   = (unsigned short*)alloc((size_t)ROWS * Dm * 2);      // 16.8 MB
    unsigned short* qk    = (unsigned short*)alloc((size_t)3 * ROWS * 512 * 2); // 100.7 MB
    unsigned short* v_cur = (unsigned short*)alloc((size_t)ROWS * Dm * 2);      // 16.8 MB
    float*          gout  = (float*)alloc((size_t)ROWS * Dm * 4);               // 33.5 MB
    unsigned short* h1    = (unsigned short*)alloc((size_t)ROWS * Ff * 2);      // 33.5 MB
    unsigned short* o_b   = h1;   // alias: o_b dead before h1 is written
    unsigned short* wTqkv = (unsigned short*)alloc((size_t)3 * 768 * 256 * 2);
    unsigned short* wTo   = (unsigned short*)alloc((size_t)3 * 256 * 256 * 2);
    unsigned short* wT1   = (unsigned short*)alloc((size_t)3 * 512 * 256 * 2);
    unsigned short* wT2   = (unsigned short*)alloc((size_t)3 * 256 * 512 * 2);
    float*          bqkv  = (float*)alloc((size_t)3 * 768 * 4);

    k_biasqkv<<<9, 256, 0, stream>>>(bqp, bkp, bvp, bqkv);
    k_transpose<<<3 * 256 * 256 / 256, 256, 0, stream>>>(Wq, wTqkv, 256, 256, 768 * 256, 0);
    k_transpose<<<3 * 256 * 256 / 256, 256, 0, stream>>>(Wk, wTqkv, 256, 256, 768 * 256, 256 * 256);
    k_transpose<<<3 * 256 * 256 / 256, 256, 0, stream>>>(Wv, wTqkv, 256, 256, 768 * 256, 512 * 256);
    k_transpose<<<3 * 256 * 256 / 256, 256, 0, stream>>>(Wo, wTo, 256, 256, 256 * 256, 0);
    k_transpose<<<3 * 256 * 512 / 256, 256, 0, stream>>>(W1, wT1, 256, 512, 512 * 256, 0);
    k_transpose<<<3 * 512 * 256 / 256, 256, 0, stream>>>(W2, wT2, 512, 256, 256 * 512, 0);
    k_embed<<<ROWS, 256, 0, stream>>>(x, WP, bP, Wpos, z_f32, z_b);

    for (int l = 0; l < 3; l++) {
        // fused QKV projection: N = 768, split epilogue -> qk history + v
        k_gemm<0, 2><<<dim3(ROWS / 128, 6), 256, 0, stream>>>(
            z_b, wTqkv + (long)l * 768 * 256, bqkv + l * 768,
            qk + (long)l * QK_LSTR, nullptr, v_cur, ROWS, 768, 256);
        // attention with score-carry recompute
        k_attn<<<Bq * 16, 256, 0, stream>>>(qk, v_cur, abias, o_b, l);
        // O projection (f32 out for residual)
        k_gemm<0, 1><<<dim3(ROWS / 128, 2), 256, 0, stream>>>(
            o_b, wTo + (long)l * 256 * 256, bo + l * 256, nullptr, gout, nullptr, ROWS, 256, 256);
        k_addln<<<ROWS / 4, 256, 0, stream>>>(z_f32, gout, g1 + l * 256, be1 + l * 256, z_f32, z_b);
        // FFN
        k_gemm<1, 0><<<dim3(ROWS / 128, 4), 256, 0, stream>>>(
            z_b, wT1 + (long)l * 512 * 256, b1 + l * 512, h1, nullptr, nullptr, ROWS, 512, 256);
        k_gemm<0, 1><<<dim3(ROWS / 128, 2), 256, 0, stream>>>(
            h1, wT2 + (long)l * 256 * 512, b2 + l * 256, nullptr, gout, nullptr, ROWS, 256, 512);
        // last layer: write f32 result straight to d_out (reference output is f32)
        float* zf_out = (l == 2) ? (float*)d_out : z_f32;
        k_addln<<<ROWS / 4, 256, 0, stream>>>(z_f32, gout, g2 + l * 256, be2 + l * 256, zf_out, z_b);
    }
}

// Round 4
// 673.393 us; speedup vs baseline: 1.0827x; 1.0827x over previous
//
#include <hip/hip_runtime.h>

#define DEV __device__ __forceinline__

typedef float          f32x4  __attribute__((ext_vector_type(4)));
typedef __bf16         bf16x8 __attribute__((ext_vector_type(8)));
typedef unsigned short u16x8  __attribute__((ext_vector_type(8)));
typedef unsigned short u16x4  __attribute__((ext_vector_type(4)));

static constexpr int  Bq   = 256;   // batch
static constexpr int  Qs   = 128;   // seq len
static constexpr int  Dm   = 256;   // model dim
static constexpr int  Ff   = 512;   // ffn dim
static constexpr int  ROWS = Bq * Qs;               // 32768
static constexpr long QK_LSTR = (long)ROWS * 512;   // q||k history per layer (head-major)

DEV unsigned short f2b(float f) {
    unsigned int u; __builtin_memcpy(&u, &f, 4);
    u += 0x7fffu + ((u >> 16) & 1u);   // RNE
    return (unsigned short)(u >> 16);
}
DEV f32x4 mfma_bf16(u16x8 a, u16x8 b, f32x4 c) {
    return __builtin_amdgcn_mfma_f32_16x16x32_bf16(
        __builtin_bit_cast(bf16x8, a), __builtin_bit_cast(bf16x8, b), c, 0, 0, 0);
}
// async global->LDS, 16B per lane; LDS dst must be wave-uniform base + lane*16
DEV void gl_lds16(const unsigned short* g, unsigned short* l) {
    __builtin_amdgcn_global_load_lds(
        (const __attribute__((address_space(1))) unsigned int*)g,
        (__attribute__((address_space(3))) unsigned int*)l, 16, 0, 0);
}

// ---------------- embed: z = x @ W_P + b_P + W_pos (all f32 in) ----------------
__global__ void k_embed(const float* __restrict__ x,
                        const float* __restrict__ WP,
                        const float* __restrict__ bP,
                        const float* __restrict__ Wpos,
                        float* __restrict__ zf, unsigned short* __restrict__ zb) {
    int row = blockIdx.x;            // b*Q + q
    int d   = threadIdx.x;           // 0..255
    int q   = row & (Qs - 1);
    const float* xr = x + row * 16;
    float acc = bP[d] + Wpos[q * Dm + d];
#pragma unroll
    for (int p = 0; p < 16; p++) acc += xr[p] * WP[p * Dm + d];
    zf[(long)row * Dm + d] = acc;
    zb[(long)row * Dm + d] = f2b(acc);
}

// ---------------- weight transpose+cast: out_bf16[N x K] = in_f32[K x N]^T, L slices ----------------
__global__ void k_transpose(const float* __restrict__ in,
                            unsigned short* __restrict__ out,
                            int K, int N, long outSlice, long outOff) {
    long idx = (long)blockIdx.x * blockDim.x + threadIdx.x;
    int per = K * N;
    int l = (int)(idx / per);
    int r = (int)(idx - (long)l * per);
    int n = r / K;
    int k = r - n * K;
    out[(long)l * outSlice + outOff + (long)n * K + k] = f2b(in[(long)l * per + (long)k * N + n]);
}

// ---------------- pack bq|bk|bv into (3,768) f32 ----------------
__global__ void k_biasqkv(const float* __restrict__ bq,
                          const float* __restrict__ bk,
                          const float* __restrict__ bv,
                          float* __restrict__ o) {
    int idx = blockIdx.x * 256 + threadIdx.x;   // < 2304
    int l = idx / 768, j = idx % 768;
    float v = (j < 256) ? bq[l * 256 + j]
            : (j < 512) ? bk[l * 256 + j - 256]
                        : bv[l * 256 + j - 512];
    o[idx] = v;
}

// ---------------- GEMM: C = act(A[MxK] @ W[KxN] + bias), W given as WT[NxK] bf16 ----------------
// 128x128 block tile, 4 waves in 2x2 quadrants of 64x64, 16x16x32 bf16 MFMA, BK=32,
// async global_load_lds staging (16B/lane).
// MODE: 0 = bf16 out (stride N), 1 = f32 out (stride N),
//       2 = qkv split: col<512 -> head-major qk history [b][h][{q,k}][row][dk], col>=512 -> v (stride 256)
template <int GELU, int MODE>
__global__ __launch_bounds__(256) void k_gemm(const unsigned short* __restrict__ A,
                                              const unsigned short* __restrict__ WT,
                                              const float* __restrict__ bias,
                                              unsigned short* __restrict__ outB,
                                              float* __restrict__ outF,
                                              unsigned short* __restrict__ aux,
                                              int M, int N, int K) {
    __shared__ unsigned short As[128 * 32];
    __shared__ unsigned short Bs[128 * 32];
    const int tid  = threadIdx.x;
    const int wave = tid >> 6, lane = tid & 63, quad = lane >> 4, l16 = lane & 15;
    const int mq = wave >> 1, nq = wave & 1;
    const int m_blk = blockIdx.x * 128, n_blk = blockIdx.y * 128;
    // staging chunk coords (16B chunks, lane-linear in LDS: base + lane*16)
    const int c0 = tid, c1 = tid + 256;
    const int ra0 = c0 >> 2, ca0 = (c0 & 3) * 8;
    const int ra1 = c1 >> 2, ca1 = (c1 & 3) * 8;

    f32x4 acc[4][4] = {};

    for (int k0 = 0; k0 < K; k0 += 32) {
        gl_lds16(A  + (long)(m_blk + ra0) * K + k0 + ca0, &As[c0 * 8]);
        gl_lds16(A  + (long)(m_blk + ra1) * K + k0 + ca1, &As[c1 * 8]);
        gl_lds16(WT + (long)(n_blk + ra0) * K + k0 + ca0, &Bs[c0 * 8]);
        gl_lds16(WT + (long)(n_blk + ra1) * K + k0 + ca1, &Bs[c1 * 8]);
        __syncthreads();
        u16x8 af[4], bf[4];
#pragma unroll
        for (int i = 0; i < 4; i++)
            af[i] = *(const u16x8*)&As[(64 * mq + 16 * i + l16) * 32 + quad * 8];
#pragma unroll
        for (int j = 0; j < 4; j++)
            bf[j] = *(const u16x8*)&Bs[(64 * nq + 16 * j + l16) * 32 + quad * 8];
#pragma unroll
        for (int i = 0; i < 4; i++)
#pragma unroll
            for (int j = 0; j < 4; j++)
                acc[i][j] = mfma_bf16(af[i], bf[j], acc[i][j]);
        __syncthreads();
    }

#pragma unroll
    for (int i = 0; i < 4; i++) {
        int row = m_blk + 64 * mq + 16 * i + quad * 4;   // C row = quad*4 + reg
#pragma unroll
        for (int j = 0; j < 4; j++) {
            int col = n_blk + 64 * nq + 16 * j + l16;    // C col = lane&15
            float bb = bias[col];
#pragma unroll
            for (int r = 0; r < 4; r++) {
                float v = acc[i][j][r] + bb;
                if (GELU) v = 0.5f * v * (1.0f + erff(v * 0.70710678118f));
                if (MODE == 0) outB[(long)(row + r) * N + col] = f2b(v);
                if (MODE == 1) outF[(long)(row + r) * N + col] = v;
                if (MODE == 2) {
                    int grow = row + r, b = grow >> 7, rin = grow & 127;
                    if (col < 512) {
                        int s = col >> 8, hh = (col >> 4) & 15, dk = col & 15;
                        outB[((long)((b * 16 + hh) * 2 + s)) * 2048 + rin * 16 + dk] = f2b(v);
                    } else {
                        aux[(long)grow * 256 + (col - 512)] = f2b(v);
                    }
                }
            }
        }
    }
}

// ---------------- fused attention for layer L (score-carry recompute) ----------------
// grid = B*H blocks; block = 256 thr (4 waves, 32 S-rows each).
// qkh layout: [l][b][h][{q,k}][row(128)][dk(16)] bf16 -> MFMA fragments load straight from global.
// S = scale * sum_{i<=L} q_i k_i^T + (L+1)*bias ; P = softmax(S) ; O = P @ v_L
template <int L>
__global__ __launch_bounds__(256) void k_attn(const unsigned short* __restrict__ qkh,
                                              const unsigned short* __restrict__ vbuf,
                                              const float* __restrict__ ab,
                                              unsigned short* __restrict__ o_out) {
    __shared__ unsigned short vt[16 * 136];   // v^T [dk][key]
    __shared__ unsigned short Ps[128 * 136];  // probs, ld 136
    const int tid  = threadIdx.x;
    const int wave = tid >> 6, lane = tid & 63, quad = lane >> 4, l16 = lane & 15;
    const int b = blockIdx.x >> 4, h = blockIdx.x & 15;
    const int qrow = tid >> 1, half = tid & 1;

    // issue v load early (consumed after QK loop)
    u16x8 vv = *(const u16x8*)(vbuf + (long)(b * Qs + qrow) * 256 + h * 16 + half * 8);

    f32x4 accS[2][8] = {};
    u16x8 zero = {};

#pragma unroll
    for (int li = 0; li <= L; li++) {
        const unsigned short* qt = qkh + ((long)((li * Bq + b) * 16 + h) * 2) * 2048;
        const unsigned short* kt = qt + 2048;
        u16x8 af[2], bf8[8];
#pragma unroll
        for (int i = 0; i < 2; i++) {
            int m = 32 * wave + 16 * i + l16;
            af[i] = (quad < 2) ? *(const u16x8*)(qt + m * 16 + quad * 8) : zero;  // K=16: quads 2,3 zero
        }
#pragma unroll
        for (int j = 0; j < 8; j++) {
            int n = 16 * j + l16;
            bf8[j] = (quad < 2) ? *(const u16x8*)(kt + n * 16 + quad * 8) : zero;
        }
#pragma unroll
        for (int i = 0; i < 2; i++)
#pragma unroll
            for (int j = 0; j < 8; j++)
                accS[i][j] = mfma_bf16(af[i], bf8[j], accS[i][j]);
    }

    // stage v^T
#pragma unroll
    for (int jj = 0; jj < 8; jj++) vt[(half * 8 + jj) * 136 + qrow] = vv[jj];

    // scale + bias + row softmax -> Ps (bf16)
    const float scale = 0.25f;            // DK^-0.5, DK=16
    const float bm = (float)(L + 1);      // bias accumulates once per layer in the carry
#pragma unroll
    for (int i = 0; i < 2; i++) {
#pragma unroll
        for (int r = 0; r < 4; r++) {
            int m = 32 * wave + 16 * i + quad * 4 + r;
            float vals[8];
#pragma unroll
            for (int j = 0; j < 8; j++)
                vals[j] = accS[i][j][r] * scale + bm * ab[m * 128 + 16 * j + l16];
            float mx = vals[0];
#pragma unroll
            for (int j = 1; j < 8; j++) mx = fmaxf(mx, vals[j]);
            for (int mk = 1; mk < 16; mk <<= 1) mx = fmaxf(mx, __shfl_xor(mx, mk));
            float sum = 0.f;
#pragma unroll
            for (int j = 0; j < 8; j++) { vals[j] = __expf(vals[j] - mx); sum += vals[j]; }
            for (int mk = 1; mk < 16; mk <<= 1) sum += __shfl_xor(sum, mk);
            float inv = 1.0f / sum;
#pragma unroll
            for (int j = 0; j < 8; j++) Ps[m * 136 + 16 * j + l16] = f2b(vals[j] * inv);
        }
    }
    __syncthreads();

    // O = P @ v : M=128, N=16, K=128
    f32x4 accO[2] = {};
#pragma unroll
    for (int s = 0; s < 4; s++) {
        u16x8 bv = *(const u16x8*)&vt[l16 * 136 + s * 32 + quad * 8];
#pragma unroll
        for (int i = 0; i < 2; i++) {
            u16x8 ap = *(const u16x8*)&Ps[(32 * wave + 16 * i + l16) * 136 + s * 32 + quad * 8];
            accO[i] = mfma_bf16(ap, bv, accO[i]);
        }
    }
#pragma unroll
    for (int i = 0; i < 2; i++)
#pragma unroll
        for (int r = 0; r < 4; r++) {
            int m = 32 * wave + 16 * i + quad * 4 + r;
            o_out[(long)(b * Qs + m) * Dm + h * 16 + l16] = f2b(accO[i][r]);
        }
}

// ---------------- residual add + LayerNorm (wave per row), f32 params ----------------
__global__ __launch_bounds__(256) void k_addln(const float* __restrict__ zin,
                                               const float* __restrict__ add,
                                               const float* __restrict__ g,
                                               const float* __restrict__ bb,
                                               float* __restrict__ zf,
                                               unsigned short* __restrict__ zb) {
    int row  = blockIdx.x * 4 + (threadIdx.x >> 6);
    int lane = threadIdx.x & 63;
    const float4 zv = *(const float4*)(zin + (long)row * Dm + lane * 4);
    const float4 av = *(const float4*)(add + (long)row * Dm + lane * 4);
    float s[4] = {zv.x + av.x, zv.y + av.y, zv.z + av.z, zv.w + av.w};
    float sum = s[0] + s[1] + s[2] + s[3];
    for (int mk = 1; mk < 64; mk <<= 1) sum += __shfl_xor(sum, mk);
    float mean = sum * (1.0f / 256.0f);
    float d0[4], var = 0.f;
#pragma unroll
    for (int c = 0; c < 4; c++) { d0[c] = s[c] - mean; var += d0[c] * d0[c]; }
    for (int mk = 1; mk < 64; mk <<= 1) var += __shfl_xor(var, mk);
    float rstd = rsqrtf(var * (1.0f / 256.0f) + 1e-5f);
    float o[4]; u16x4 ob;
#pragma unroll
    for (int c = 0; c < 4; c++) {
        int col = lane * 4 + c;
        o[c] = d0[c] * rstd * g[col] + bb[col];
        ob[c] = f2b(o[c]);
    }
    *(float4*)(zf + (long)row * Dm + lane * 4) = make_float4(o[0], o[1], o[2], o[3]);
    *(u16x4*)(zb + (long)row * Dm + lane * 4) = ob;
}

extern "C" void kernel_launch(void* const* d_in, const int* in_sizes, int n_in,
                              void* d_out, int out_size, void* d_ws, size_t ws_size,
                              hipStream_t stream) {
    const float* x     = (const float*)d_in[0];
    const float* abias = (const float*)d_in[1];
    const float* WP    = (const float*)d_in[2];
    const float* bP    = (const float*)d_in[3];
    const float* Wpos  = (const float*)d_in[4];
    const float* Wq    = (const float*)d_in[5];
    const float* bqp   = (const float*)d_in[6];
    const float* Wk    = (const float*)d_in[7];
    const float* bkp   = (const float*)d_in[8];
    const float* Wv    = (const float*)d_in[9];
    const float* bvp   = (const float*)d_in[10];
    const float* Wo    = (const float*)d_in[11];
    const float* bo    = (const float*)d_in[12];
    const float* g1    = (const float*)d_in[13];
    const float* be1   = (const float*)d_in[14];
    const float* W1    = (const float*)d_in[15];
    const float* b1    = (const float*)d_in[16];
    const float* W2    = (const float*)d_in[17];
    const float* b2    = (const float*)d_in[18];
    const float* g2    = (const float*)d_in[19];
    const float* be2   = (const float*)d_in[20];
    (void)in_sizes; (void)n_in; (void)out_size; (void)ws_size;

    char* ws = (char*)d_ws;
    size_t off = 0;
    auto alloc = [&](size_t bytes) -> char* {
        char* p = ws + off; off += (bytes + 255) & ~(size_t)255; return p;
    };
    // total ~238 MB of workspace (fits 256 MiB)
    float*          z_f32 = (float*)alloc((size_t)ROWS * Dm * 4);               // 33.5 MB
    unsigned short* z_b   = (unsigned short*)alloc((size_t)ROWS * Dm * 2);      // 16.8 MB
    unsigned short* qkh   = (unsigned short*)alloc((size_t)3 * ROWS * 512 * 2); // 100.7 MB head-major
    unsigned short* v_cur = (unsigned short*)alloc((size_t)ROWS * Dm * 2);      // 16.8 MB
    float*          gout  = (float*)alloc((size_t)ROWS * Dm * 4);               // 33.5 MB
    unsigned short* h1    = (unsigned short*)alloc((size_t)ROWS * Ff * 2);      // 33.5 MB
    unsigned short* o_b   = h1;   // alias: o_b dead before h1 is written
    unsigned short* wTqkv = (unsigned short*)alloc((size_t)3 * 768 * 256 * 2);
    unsigned short* wTo   = (unsigned short*)alloc((size_t)3 * 256 * 256 * 2);
    unsigned short* wT1   = (unsigned short*)alloc((size_t)3 * 512 * 256 * 2);
    unsigned short* wT2   = (unsigned short*)alloc((size_t)3 * 256 * 512 * 2);
    float*          bqkv  = (float*)alloc((size_t)3 * 768 * 4);

    k_biasqkv<<<9, 256, 0, stream>>>(bqp, bkp, bvp, bqkv);
    k_transpose<<<3 * 256 * 256 / 256, 256, 0, stream>>>(Wq, wTqkv, 256, 256, 768 * 256, 0);
    k_transpose<<<3 * 256 * 256 / 256, 256, 0, stream>>>(Wk, wTqkv, 256, 256, 768 * 256, 256 * 256);
    k_transpose<<<3 * 256 * 256 / 256, 256, 0, stream>>>(Wv, wTqkv, 256, 256, 768 * 256, 512 * 256);
    k_transpose<<<3 * 256 * 256 / 256, 256, 0, stream>>>(Wo, wTo, 256, 256, 256 * 256, 0);
    k_transpose<<<3 * 256 * 512 / 256, 256, 0, stream>>>(W1, wT1, 256, 512, 512 * 256, 0);
    k_transpose<<<3 * 512 * 256 / 256, 256, 0, stream>>>(W2, wT2, 512, 256, 256 * 512, 0);
    k_embed<<<ROWS, 256, 0, stream>>>(x, WP, bP, Wpos, z_f32, z_b);

    for (int l = 0; l < 3; l++) {
        // fused QKV projection: N = 768, split epilogue -> head-major qk history + v
        k_gemm<0, 2><<<dim3(ROWS / 128, 6), 256, 0, stream>>>(
            z_b, wTqkv + (long)l * 768 * 256, bqkv + l * 768,
            qkh + (long)l * QK_LSTR, nullptr, v_cur, ROWS, 768, 256);
        // attention with score-carry recompute (templated on layer for unroll)
        if (l == 0)      k_attn<0><<<Bq * 16, 256, 0, stream>>>(qkh, v_cur, abias, o_b);
        else if (l == 1) k_attn<1><<<Bq * 16, 256, 0, stream>>>(qkh, v_cur, abias, o_b);
        else             k_attn<2><<<Bq * 16, 256, 0, stream>>>(qkh, v_cur, abias, o_b);
        // O projection (f32 out for residual)
        k_gemm<0, 1><<<dim3(ROWS / 128, 2), 256, 0, stream>>>(
            o_b, wTo + (long)l * 256 * 256, bo + l * 256, nullptr, gout, nullptr, ROWS, 256, 256);
        k_addln<<<ROWS / 4, 256, 0, stream>>>(z_f32, gout, g1 + l * 256, be1 + l * 256, z_f32, z_b);
        // FFN
        k_gemm<1, 0><<<dim3(ROWS / 128, 4), 256, 0, stream>>>(
            z_b, wT1 + (long)l * 512 * 256, b1 + l * 512, h1, nullptr, nullptr, ROWS, 512, 256);
        k_gemm<0, 1><<<dim3(ROWS / 128, 2), 256, 0, stream>>>(
            h1, wT2 + (long)l * 256 * 512, b2 + l * 256, nullptr, gout, nullptr, ROWS, 256, 512);
        // last layer: write f32 result straight to d_out (reference output is f32)
        float* zf_out = (l == 2) ? (float*)d_out : z_f32;
        k_addln<<<ROWS / 4, 256, 0, stream>>>(z_f32, gout, g2 + l * 256, be2 + l * 256, zf_out, z_b);
    }
}

// Round 5
// 579.714 us; speedup vs baseline: 1.2576x; 1.1616x over previous
//
#include <hip/hip_runtime.h>

#define DEV __device__ __forceinline__

typedef float          f32x4  __attribute__((ext_vector_type(4)));
typedef __bf16         bf16x8 __attribute__((ext_vector_type(8)));
typedef unsigned short u16x8  __attribute__((ext_vector_type(8)));
typedef unsigned short u16x4  __attribute__((ext_vector_type(4)));

static constexpr int  Bq   = 256;   // batch
static constexpr int  Qs   = 128;   // seq len
static constexpr int  Dm   = 256;   // model dim
static constexpr int  Ff   = 512;   // ffn dim
static constexpr int  ROWS = Bq * Qs;               // 32768
static constexpr long QK_LSTR = (long)ROWS * 512;   // q||k history per layer (head-major)

DEV float b2f(unsigned short h) {
    unsigned int u = ((unsigned int)h) << 16;
    float f; __builtin_memcpy(&f, &u, 4); return f;
}
DEV unsigned short f2b(float f) {
    unsigned int u; __builtin_memcpy(&u, &f, 4);
    u += 0x7fffu + ((u >> 16) & 1u);   // RNE
    return (unsigned short)(u >> 16);
}
DEV f32x4 mfma_bf16(u16x8 a, u16x8 b, f32x4 c) {
    return __builtin_amdgcn_mfma_f32_16x16x32_bf16(
        __builtin_bit_cast(bf16x8, a), __builtin_bit_cast(bf16x8, b), c, 0, 0, 0);
}
// async global->LDS, 16B per lane; LDS dst must be wave-uniform base + lane*16
DEV void gl_lds16(const unsigned short* g, unsigned short* l) {
    __builtin_amdgcn_global_load_lds(
        (const __attribute__((address_space(1))) unsigned int*)g,
        (__attribute__((address_space(3))) unsigned int*)l, 16, 0, 0);
}

// ---------------- embed: z = x @ W_P + b_P + W_pos (all f32 in), bf16 out ----------------
__global__ void k_embed(const float* __restrict__ x,
                        const float* __restrict__ WP,
                        const float* __restrict__ bP,
                        const float* __restrict__ Wpos,
                        unsigned short* __restrict__ zb) {
    int row = blockIdx.x;            // b*Q + q
    int d   = threadIdx.x;           // 0..255
    int q   = row & (Qs - 1);
    const float* xr = x + row * 16;
    float acc = bP[d] + Wpos[q * Dm + d];
#pragma unroll
    for (int p = 0; p < 16; p++) acc += xr[p] * WP[p * Dm + d];
    zb[(long)row * Dm + d] = f2b(acc);
}

// ---------------- weight transpose+cast: out_bf16[N x K] = in_f32[K x N]^T, L slices ----------------
__global__ void k_transpose(const float* __restrict__ in,
                            unsigned short* __restrict__ out,
                            int K, int N, long outSlice, long outOff) {
    long idx = (long)blockIdx.x * blockDim.x + threadIdx.x;
    int per = K * N;
    int l = (int)(idx / per);
    int r = (int)(idx - (long)l * per);
    int n = r / K;
    int k = r - n * K;
    out[(long)l * outSlice + outOff + (long)n * K + k] = f2b(in[(long)l * per + (long)k * N + n]);
}

// ---------------- pack bq|bk|bv into (3,768) f32 ----------------
__global__ void k_biasqkv(const float* __restrict__ bq,
                          const float* __restrict__ bk,
                          const float* __restrict__ bv,
                          float* __restrict__ o) {
    int idx = blockIdx.x * 256 + threadIdx.x;   // < 2304
    int l = idx / 768, j = idx % 768;
    float v = (j < 256) ? bq[l * 256 + j]
            : (j < 512) ? bk[l * 256 + j - 256]
                        : bv[l * 256 + j - 512];
    o[idx] = v;
}

// ---------------- GEMM: C = act(A[MxK] @ W[KxN] + bias), W given as WT[NxK] bf16 ----------------
// 128x128 tile, 4 waves 2x2, 16x16x32 bf16 MFMA, BK=32, global_load_lds staging.
// MODE: 0 = bf16 out (stride N),
//       2 = qkv split: col<512 -> head-major qk history [b][h][{q,k}][row][dk], col>=512 -> v (stride 256)
template <int GELU, int MODE>
__global__ __launch_bounds__(256) void k_gemm(const unsigned short* __restrict__ A,
                                              const unsigned short* __restrict__ WT,
                                              const float* __restrict__ bias,
                                              unsigned short* __restrict__ outB,
                                              unsigned short* __restrict__ aux,
                                              int M, int N, int K) {
    __shared__ unsigned short As[128 * 32];
    __shared__ unsigned short Bs[128 * 32];
    const int tid  = threadIdx.x;
    const int wave = tid >> 6, lane = tid & 63, quad = lane >> 4, l16 = lane & 15;
    const int mq = wave >> 1, nq = wave & 1;
    const int m_blk = blockIdx.x * 128, n_blk = blockIdx.y * 128;
    const int c0 = tid, c1 = tid + 256;
    const int ra0 = c0 >> 2, ca0 = (c0 & 3) * 8;
    const int ra1 = c1 >> 2, ca1 = (c1 & 3) * 8;

    f32x4 acc[4][4] = {};

    for (int k0 = 0; k0 < K; k0 += 32) {
        gl_lds16(A  + (long)(m_blk + ra0) * K + k0 + ca0, &As[c0 * 8]);
        gl_lds16(A  + (long)(m_blk + ra1) * K + k0 + ca1, &As[c1 * 8]);
        gl_lds16(WT + (long)(n_blk + ra0) * K + k0 + ca0, &Bs[c0 * 8]);
        gl_lds16(WT + (long)(n_blk + ra1) * K + k0 + ca1, &Bs[c1 * 8]);
        __syncthreads();
        u16x8 af[4], bf[4];
#pragma unroll
        for (int i = 0; i < 4; i++)
            af[i] = *(const u16x8*)&As[(64 * mq + 16 * i + l16) * 32 + quad * 8];
#pragma unroll
        for (int j = 0; j < 4; j++)
            bf[j] = *(const u16x8*)&Bs[(64 * nq + 16 * j + l16) * 32 + quad * 8];
#pragma unroll
        for (int i = 0; i < 4; i++)
#pragma unroll
            for (int j = 0; j < 4; j++)
                acc[i][j] = mfma_bf16(af[i], bf[j], acc[i][j]);
        __syncthreads();
    }

#pragma unroll
    for (int i = 0; i < 4; i++) {
        int row = m_blk + 64 * mq + 16 * i + quad * 4;   // C row = quad*4 + reg
#pragma unroll
        for (int j = 0; j < 4; j++) {
            int col = n_blk + 64 * nq + 16 * j + l16;    // C col = lane&15
            float bb = bias[col];
#pragma unroll
            for (int r = 0; r < 4; r++) {
                float v = acc[i][j][r] + bb;
                if (GELU) v = 0.5f * v * (1.0f + erff(v * 0.70710678118f));
                if (MODE == 0) outB[(long)(row + r) * N + col] = f2b(v);
                if (MODE == 2) {
                    int grow = row + r, b = grow >> 7, rin = grow & 127;
                    if (col < 512) {
                        int s = col >> 8, hh = (col >> 4) & 15, dk = col & 15;
                        outB[((long)((b * 16 + hh) * 2 + s)) * 2048 + rin * 16 + dk] = f2b(v);
                    } else {
                        aux[(long)grow * 256 + (col - 512)] = f2b(v);
                    }
                }
            }
        }
    }
}

// ---------------- fused GEMM + residual + LayerNorm ----------------
// C = LN( Zres + A[Mx K] @ W[K x 256] + bias ; g, be ).  Tile 64 rows x 256 cols (full row).
// 4 waves side by side in N (wave w -> cols 64w..64w+63). Residual tile prefetched to LDS.
template <int LAST>
__global__ __launch_bounds__(256) void k_gemm_ln(const unsigned short* __restrict__ A,
                                                 const unsigned short* __restrict__ WT,
                                                 const float* __restrict__ bias,
                                                 const unsigned short* __restrict__ Zres,
                                                 const float* __restrict__ g,
                                                 const float* __restrict__ be,
                                                 unsigned short* __restrict__ zb,
                                                 float* __restrict__ outF,
                                                 int K) {
    // LDS: Zs 32KB | As 4KB | Bs 16KB ; stats (2KB) aliases As after K-loop
    __shared__ unsigned short smem[16384 + 2048 + 8192];
    unsigned short* Zs = smem;
    unsigned short* As = smem + 16384;
    unsigned short* Bs = smem + 16384 + 2048;
    float2* stats = (float2*)(smem + 16384);   // [row(64)][wave(4)]

    const int tid  = threadIdx.x;
    const int wave = tid >> 6, lane = tid & 63, quad = lane >> 4, l16 = lane & 15;
    const int m_blk = blockIdx.x * 64;

    // prefetch residual tile (64x256 bf16 = 32KB): 8 chunks/thread, lane-linear
#pragma unroll
    for (int s = 0; s < 8; s++) {
        int c = tid + 256 * s;
        int zr = c >> 5, zc = (c & 31) * 8;
        gl_lds16(Zres + (long)(m_blk + zr) * 256 + zc, &Zs[c * 8]);
    }

    const int ca = (tid & 3) * 8, raA = tid >> 2;   // A chunk coords (1/thread)
    f32x4 acc[4][4] = {};

    for (int k0 = 0; k0 < K; k0 += 32) {
        gl_lds16(A + (long)(m_blk + raA) * K + k0 + ca, &As[tid * 8]);
#pragma unroll
        for (int s = 0; s < 4; s++) {
            int c = tid + 256 * s;
            int br = c >> 2, bc = (c & 3) * 8;
            gl_lds16(WT + (long)br * K + k0 + bc, &Bs[c * 8]);
        }
        __syncthreads();
        u16x8 af[4], bf[4];
#pragma unroll
        for (int i = 0; i < 4; i++)
            af[i] = *(const u16x8*)&As[(16 * i + l16) * 32 + quad * 8];
#pragma unroll
        for (int j = 0; j < 4; j++)
            bf[j] = *(const u16x8*)&Bs[(64 * wave + 16 * j + l16) * 32 + quad * 8];
#pragma unroll
        for (int i = 0; i < 4; i++)
#pragma unroll
            for (int j = 0; j < 4; j++)
                acc[i][j] = mfma_bf16(af[i], bf[j], acc[i][j]);
        __syncthreads();
    }

    // epilogue: v = acc + bias + residual; row stats; LN; store
    float bb[4], gg[4], bt[4];
#pragma unroll
    for (int j = 0; j < 4; j++) {
        int col = 64 * wave + 16 * j + l16;
        bb[j] = bias[col]; gg[j] = g[col]; bt[j] = be[col];
    }
#pragma unroll
    for (int i = 0; i < 4; i++) {
#pragma unroll
        for (int r = 0; r < 4; r++) {
            int rloc = 16 * i + quad * 4 + r;
            float s1 = 0.f, s2 = 0.f;
#pragma unroll
            for (int j = 0; j < 4; j++) {
                int col = 64 * wave + 16 * j + l16;
                float v = acc[i][j][r] + bb[j] + b2f(Zs[rloc * 256 + col]);
                acc[i][j][r] = v;
                s1 += v; s2 += v * v;
            }
            for (int mk = 1; mk < 16; mk <<= 1) {
                s1 += __shfl_xor(s1, mk);
                s2 += __shfl_xor(s2, mk);
            }
            if (l16 == 0) stats[rloc * 4 + wave] = make_float2(s1, s2);
        }
    }
    __syncthreads();
#pragma unroll
    for (int i = 0; i < 4; i++) {
#pragma unroll
        for (int r = 0; r < 4; r++) {
            int rloc = 16 * i + quad * 4 + r;
            f32x4 p0 = *(const f32x4*)&stats[rloc * 4];
            f32x4 p1 = *(const f32x4*)&stats[rloc * 4 + 2];
            float S1 = p0[0] + p0[2] + p1[0] + p1[2];
            float S2 = p0[1] + p0[3] + p1[1] + p1[3];
            float mean = S1 * (1.0f / 256.0f);
            float var  = S2 * (1.0f / 256.0f) - mean * mean;
            float rstd = rsqrtf(var + 1e-5f);
            long grow = m_blk + rloc;
#pragma unroll
            for (int j = 0; j < 4; j++) {
                int col = 64 * wave + 16 * j + l16;
                float o = (acc[i][j][r] - mean) * rstd * gg[j] + bt[j];
                if (LAST) outF[grow * 256 + col] = o;
                else      zb[grow * 256 + col] = f2b(o);
            }
        }
    }
}

// ---------------- fused attention for layer L (score-carry recompute) ----------------
// grid = B*H blocks; block = 256 thr (4 waves, 32 S-rows each).
// qkh layout: [l][b][h][{q,k}][row(128)][dk(16)] bf16.
// Layer-packed QK: layers 2p,2p+1 concatenated along K in one K=32 MFMA
// (quads 0-1 = layer 2p, quads 2-3 = layer 2p+1); odd tail uses half-zero K=16.
template <int L>
__global__ __launch_bounds__(256) void k_attn(const unsigned short* __restrict__ qkh,
                                              const unsigned short* __restrict__ vbuf,
                                              const float* __restrict__ ab,
                                              unsigned short* __restrict__ o_out) {
    __shared__ unsigned short vt[16 * 136];   // v^T [dk][key]
    __shared__ unsigned short Ps[128 * 136];  // probs, ld 136
    const int tid  = threadIdx.x;
    const int wave = tid >> 6, lane = tid & 63, quad = lane >> 4, l16 = lane & 15;
    const int b = blockIdx.x >> 4, h = blockIdx.x & 15;
    const int qrow = tid >> 1, half = tid & 1;

    // issue v load early (consumed after QK loop)
    u16x8 vv = *(const u16x8*)(vbuf + (long)(b * Qs + qrow) * 256 + h * 16 + half * 8);

    f32x4 accS[2][8] = {};
    u16x8 zero = {};

    constexpr int FULL = (L + 1) / 2;
    constexpr bool HALF = ((L + 1) & 1) != 0;

#pragma unroll
    for (int p = 0; p < FULL; p++) {
        const unsigned short* q0 = qkh + ((long)(((2 * p) * Bq + b) * 16 + h) * 2) * 2048;
        const unsigned short* q1 = qkh + ((long)(((2 * p + 1) * Bq + b) * 16 + h) * 2) * 2048;
        const unsigned short* qsel = (quad < 2) ? q0 : q1;
        const unsigned short* ksel = (quad < 2) ? (q0 + 2048) : (q1 + 2048);
        const int koff = (quad & 1) * 8;
        u16x8 af[2], bf8[8];
#pragma unroll
        for (int i = 0; i < 2; i++) {
            int m = 32 * wave + 16 * i + l16;
            af[i] = *(const u16x8*)(qsel + m * 16 + koff);
        }
#pragma unroll
        for (int j = 0; j < 8; j++) {
            int n = 16 * j + l16;
            bf8[j] = *(const u16x8*)(ksel + n * 16 + koff);
        }
#pragma unroll
        for (int i = 0; i < 2; i++)
#pragma unroll
            for (int j = 0; j < 8; j++)
                accS[i][j] = mfma_bf16(af[i], bf8[j], accS[i][j]);
    }
    if (HALF) {
        const unsigned short* qt = qkh + ((long)((L * Bq + b) * 16 + h) * 2) * 2048;
        const unsigned short* kt = qt + 2048;
        u16x8 af[2], bf8[8];
#pragma unroll
        for (int i = 0; i < 2; i++) {
            int m = 32 * wave + 16 * i + l16;
            af[i] = (quad < 2) ? *(const u16x8*)(qt + m * 16 + quad * 8) : zero;
        }
#pragma unroll
        for (int j = 0; j < 8; j++) {
            int n = 16 * j + l16;
            bf8[j] = (quad < 2) ? *(const u16x8*)(kt + n * 16 + quad * 8) : zero;
        }
#pragma unroll
        for (int i = 0; i < 2; i++)
#pragma unroll
            for (int j = 0; j < 8; j++)
                accS[i][j] = mfma_bf16(af[i], bf8[j], accS[i][j]);
    }

    // stage v^T
#pragma unroll
    for (int jj = 0; jj < 8; jj++) vt[(half * 8 + jj) * 136 + qrow] = vv[jj];

    // scale + bias + row softmax -> Ps (bf16)
    const float scale = 0.25f;            // DK^-0.5, DK=16
    const float bm = (float)(L + 1);      // bias accumulates once per layer in the carry
#pragma unroll
    for (int i = 0; i < 2; i++) {
#pragma unroll
        for (int r = 0; r < 4; r++) {
            int m = 32 * wave + 16 * i + quad * 4 + r;
            float vals[8];
#pragma unroll
            for (int j = 0; j < 8; j++)
                vals[j] = accS[i][j][r] * scale + bm * ab[m * 128 + 16 * j + l16];
            float mx = vals[0];
#pragma unroll
            for (int j = 1; j < 8; j++) mx = fmaxf(mx, vals[j]);
            for (int mk = 1; mk < 16; mk <<= 1) mx = fmaxf(mx, __shfl_xor(mx, mk));
            float sum = 0.f;
#pragma unroll
            for (int j = 0; j < 8; j++) { vals[j] = __expf(vals[j] - mx); sum += vals[j]; }
            for (int mk = 1; mk < 16; mk <<= 1) sum += __shfl_xor(sum, mk);
            float inv = 1.0f / sum;
#pragma unroll
            for (int j = 0; j < 8; j++) Ps[m * 136 + 16 * j + l16] = f2b(vals[j] * inv);
        }
    }
    __syncthreads();

    // O = P @ v : M=128, N=16, K=128
    f32x4 accO[2] = {};
#pragma unroll
    for (int s = 0; s < 4; s++) {
        u16x8 bv = *(const u16x8*)&vt[l16 * 136 + s * 32 + quad * 8];
#pragma unroll
        for (int i = 0; i < 2; i++) {
            u16x8 ap = *(const u16x8*)&Ps[(32 * wave + 16 * i + l16) * 136 + s * 32 + quad * 8];
            accO[i] = mfma_bf16(ap, bv, accO[i]);
        }
    }
#pragma unroll
    for (int i = 0; i < 2; i++)
#pragma unroll
        for (int r = 0; r < 4; r++) {
            int m = 32 * wave + 16 * i + quad * 4 + r;
            o_out[(long)(b * Qs + m) * Dm + h * 16 + l16] = f2b(accO[i][r]);
        }
}

extern "C" void kernel_launch(void* const* d_in, const int* in_sizes, int n_in,
                              void* d_out, int out_size, void* d_ws, size_t ws_size,
                              hipStream_t stream) {
    const float* x     = (const float*)d_in[0];
    const float* abias = (const float*)d_in[1];
    const float* WP    = (const float*)d_in[2];
    const float* bP    = (const float*)d_in[3];
    const float* Wpos  = (const float*)d_in[4];
    const float* Wq    = (const float*)d_in[5];
    const float* bqp   = (const float*)d_in[6];
    const float* Wk    = (const float*)d_in[7];
    const float* bkp   = (const float*)d_in[8];
    const float* Wv    = (const float*)d_in[9];
    const float* bvp   = (const float*)d_in[10];
    const float* Wo    = (const float*)d_in[11];
    const float* bo    = (const float*)d_in[12];
    const float* g1    = (const float*)d_in[13];
    const float* be1   = (const float*)d_in[14];
    const float* W1    = (const float*)d_in[15];
    const float* b1    = (const float*)d_in[16];
    const float* W2    = (const float*)d_in[17];
    const float* b2    = (const float*)d_in[18];
    const float* g2    = (const float*)d_in[19];
    const float* be2   = (const float*)d_in[20];
    (void)in_sizes; (void)n_in; (void)out_size; (void)ws_size;

    char* ws = (char*)d_ws;
    size_t off = 0;
    auto alloc = [&](size_t bytes) -> char* {
        char* p = ws + off; off += (bytes + 255) & ~(size_t)255; return p;
    };
    // ~172 MB of workspace
    unsigned short* z_b   = (unsigned short*)alloc((size_t)ROWS * Dm * 2);      // 16.8 MB
    unsigned short* qkh   = (unsigned short*)alloc((size_t)3 * ROWS * 512 * 2); // 100.7 MB head-major
    unsigned short* v_cur = (unsigned short*)alloc((size_t)ROWS * Dm * 2);      // 16.8 MB
    unsigned short* h1    = (unsigned short*)alloc((size_t)ROWS * Ff * 2);      // 33.5 MB
    unsigned short* o_b   = h1;   // alias: o_b dead before h1 is written
    unsigned short* wTqkv = (unsigned short*)alloc((size_t)3 * 768 * 256 * 2);
    unsigned short* wTo   = (unsigned short*)alloc((size_t)3 * 256 * 256 * 2);
    unsigned short* wT1   = (unsigned short*)alloc((size_t)3 * 512 * 256 * 2);
    unsigned short* wT2   = (unsigned short*)alloc((size_t)3 * 256 * 512 * 2);
    float*          bqkv  = (float*)alloc((size_t)3 * 768 * 4);

    k_biasqkv<<<9, 256, 0, stream>>>(bqp, bkp, bvp, bqkv);
    k_transpose<<<3 * 256 * 256 / 256, 256, 0, stream>>>(Wq, wTqkv, 256, 256, 768 * 256, 0);
    k_transpose<<<3 * 256 * 256 / 256, 256, 0, stream>>>(Wk, wTqkv, 256, 256, 768 * 256, 256 * 256);
    k_transpose<<<3 * 256 * 256 / 256, 256, 0, stream>>>(Wv, wTqkv, 256, 256, 768 * 256, 512 * 256);
    k_transpose<<<3 * 256 * 256 / 256, 256, 0, stream>>>(Wo, wTo, 256, 256, 256 * 256, 0);
    k_transpose<<<3 * 256 * 512 / 256, 256, 0, stream>>>(W1, wT1, 256, 512, 512 * 256, 0);
    k_transpose<<<3 * 512 * 256 / 256, 256, 0, stream>>>(W2, wT2, 512, 256, 256 * 512, 0);
    k_embed<<<ROWS, 256, 0, stream>>>(x, WP, bP, Wpos, z_b);

    for (int l = 0; l < 3; l++) {
        // fused QKV projection: N = 768, split epilogue -> head-major qk history + v
        k_gemm<0, 2><<<dim3(ROWS / 128, 6), 256, 0, stream>>>(
            z_b, wTqkv + (long)l * 768 * 256, bqkv + l * 768,
            qkh + (long)l * QK_LSTR, v_cur, ROWS, 768, 256);
        // attention with score-carry recompute (layer-packed K)
        if (l == 0)      k_attn<0><<<Bq * 16, 256, 0, stream>>>(qkh, v_cur, abias, o_b);
        else if (l == 1) k_attn<1><<<Bq * 16, 256, 0, stream>>>(qkh, v_cur, abias, o_b);
        else             k_attn<2><<<Bq * 16, 256, 0, stream>>>(qkh, v_cur, abias, o_b);
        // O projection + residual + LN1 (fused), bf16 residual stream
        k_gemm_ln<0><<<ROWS / 64, 256, 0, stream>>>(
            o_b, wTo + (long)l * 256 * 256, bo + l * 256, z_b,
            g1 + l * 256, be1 + l * 256, z_b, nullptr, 256);
        // FFN1 (gelu)
        k_gemm<1, 0><<<dim3(ROWS / 128, 4), 256, 0, stream>>>(
            z_b, wT1 + (long)l * 512 * 256, b1 + l * 512, h1, nullptr, ROWS, 512, 256);
        // FFN2 + residual + LN2 (fused); last layer writes f32 d_out
        if (l == 2)
            k_gemm_ln<1><<<ROWS / 64, 256, 0, stream>>>(
                h1, wT2 + (long)l * 256 * 512, b2 + l * 256, z_b,
                g2 + l * 256, be2 + l * 256, nullptr, (float*)d_out, 512);
        else
            k_gemm_ln<0><<<ROWS / 64, 256, 0, stream>>>(
                h1, wT2 + (long)l * 256 * 512, b2 + l * 256, z_b,
                g2 + l * 256, be2 + l * 256, z_b, nullptr, 512);
    }
}